// Round 13
// baseline (252.390 us; speedup 1.0000x reference)
//
#include <hip/hip_runtime.h>

#define HH 256
#define WW 256
#define CC 64
#define FF 128
#define NN 8
#define OUTC 384           // 3*C sep + C lap + F learned
#define HW (HH * WW)

typedef __attribute__((ext_vector_type(8))) short bf16x8;
typedef __attribute__((ext_vector_type(4))) float f32x4;

__device__ __forceinline__ int clampi(int v, int lo, int hi) {
    return v < lo ? lo : (v > hi ? hi : v);
}

// round-to-nearest-even fp32 -> bf16
static __device__ __forceinline__ unsigned short f2bf(float x) {
    unsigned u = __builtin_bit_cast(unsigned, x);
    u += 0x7FFFu + ((u >> 16) & 1u);
    return (unsigned short)(u >> 16);
}
static __device__ __forceinline__ unsigned packbf(float a, float b) {
    return (unsigned)f2bf(a) | ((unsigned)f2bf(b) << 16);
}
static __device__ __forceinline__ float bf2f(unsigned short s) {
    return __builtin_bit_cast(float, (unsigned)s << 16);
}
static __device__ __forceinline__ void nts4(float* p, float a, float b, float c, float d) {
    f32x4 v = {a, b, c, d};
    __builtin_nontemporal_store(v, reinterpret_cast<f32x4*>(p));
}

// ---------------------------------------------------------------------------
// k0: W[f][c][3][3] fp32 -> wsW bf16 [t][kg][f][8ch]  (9*8*128*8 = 147456 B)
// ---------------------------------------------------------------------------
__global__ __launch_bounds__(256) void wT_kernel(const float* __restrict__ Wl,
                                                 unsigned short* __restrict__ wsW) {
    int e = blockIdx.x * 256 + threadIdx.x;     // (t, kg, f): 9*8*128 = 9216
    if (e >= 9216) return;
    int t = e >> 10;
    int rem = e & 1023;
    int kg = rem >> 7;
    int f = rem & 127;
    unsigned u[4];
#pragma unroll
    for (int j2 = 0; j2 < 4; ++j2) {
        float a = Wl[(size_t)f * 576 + (size_t)(kg * 8 + 2 * j2) * 9 + t];
        float b = Wl[(size_t)f * 576 + (size_t)(kg * 8 + 2 * j2 + 1) * 9 + t];
        u[j2] = packbf(a, b);
    }
    *reinterpret_cast<uint4*>(wsW + (size_t)e * 8) = make_uint4(u[0], u[1], u[2], u[3]);
}

// ---------------------------------------------------------------------------
// k1: MIXED pack | dwA, 32768 blocks x 256 thr, interleave 1:1 in groups of 8
// (xcd = bid&7 uniform per personality). No LDS, lean VGPR -> 8 blocks/CU.
//  p==0 -> pack: x NCHW fp32 -> xt NC8HW8 bf16 for (n=xcd, cg, y).
//  p==1 -> dwA: fp32-exact depthwise (R1 body), (n=xcd, c, 4 rows), y<128.
// dwA's nt write stream hides pack's read+write; both read x (L3-shared).
// ---------------------------------------------------------------------------
__global__ __launch_bounds__(256) void k1_kernel(const float* __restrict__ x,
                                                 unsigned short* __restrict__ xt,
                                                 float* __restrict__ out) {
    int bid = blockIdx.x;
    int xcd = bid & 7;
    int p = (bid >> 3) & 1;
    int cnt = bid >> 4;                   // 0..2047 per (xcd, p)
    int n = xcd;

    if (p == 0) {
        // ---- pack ----
        int cg = cnt >> 8;                // 0..7
        int y = cnt & 255;
        int w = threadIdx.x;
        const float* xp = x + ((size_t)(n * CC + cg * 8)) * HW + (size_t)y * WW + w;
        unsigned u[4];
#pragma unroll
        for (int j2 = 0; j2 < 4; ++j2)
            u[j2] = packbf(xp[(size_t)(2 * j2) * HW], xp[(size_t)(2 * j2 + 1) * HW]);
        *reinterpret_cast<uint4*>(xt + ((size_t)((n * 8 + cg) * HH + y) * WW + w) * 8) =
            make_uint4(u[0], u[1], u[2], u[3]);
        return;
    }

    // ---- dwA: fp32 depthwise, rows y = y4*4 + r, y4 in [0,32) => y in [0,128)
    int c = cnt >> 5;                     // 0..63
    int y4 = cnt & 31;                    // 0..31
    int t = threadIdx.x;
    int r = t >> 6;                       // 0..3
    int col = (t & 63) * 4;
    int y = y4 * 4 + r;

    const float* xp = x + ((size_t)(n * CC + c)) * HW;
    int ym = y == 0 ? 0 : y - 1;
    int yp = y + 1;                       // y <= 127 -> yp <= 128, in range
    int cl = col == 0 ? 0 : col - 1;
    int cr = (col + 4 > WW - 1) ? WW - 1 : col + 4;

    float4 top = *(const float4*)(xp + (size_t)ym * WW + col);
    float4 mid = *(const float4*)(xp + (size_t)y  * WW + col);
    float4 bot = *(const float4*)(xp + (size_t)yp * WW + col);
    float tl = xp[(size_t)ym * WW + cl], tr = xp[(size_t)ym * WW + cr];
    float ml = xp[(size_t)y  * WW + cl], mr = xp[(size_t)y  * WW + cr];
    float blv = xp[(size_t)yp * WW + cl], br = xp[(size_t)yp * WW + cr];

    float tv[6] = {tl, top.x, top.y, top.z, top.w, tr};
    float mv[6] = {ml, mid.x, mid.y, mid.z, mid.w, mr};
    float bv[6] = {blv, bot.x, bot.y, bot.z, bot.w, br};

    float o0[4], o1[4], o2[4], o3[4];
#pragma unroll
    for (int j = 0; j < 4; ++j) {
        float tL = tv[j], tC = tv[j + 1], tR = tv[j + 2];
        float mL = mv[j], mC = mv[j + 1], mR = mv[j + 2];
        float bL = bv[j], bC = bv[j + 1], bR = bv[j + 2];
        o0[j] = mC;
        o1[j] = (tL + 2.0f * tC + tR) - (bL + 2.0f * bC + bR);
        o2[j] = (tL - tR) + 2.0f * (mL - mR) + (bL - bR);
        o3[j] = 4.0f * mC - tC - bC - mL - mR;
    }

    float* ob = out + ((size_t)n * OUTC) * HW + (size_t)y * WW + col;
    nts4(ob + (size_t)(c * 3 + 0) * HW, o0[0], o0[1], o0[2], o0[3]);
    nts4(ob + (size_t)(c * 3 + 1) * HW, o1[0], o1[1], o1[2], o1[3]);
    nts4(ob + (size_t)(c * 3 + 2) * HW, o2[0], o2[1], o2[2], o2[3]);
    nts4(ob + (size_t)(192 + c)   * HW, o3[0], o3[1], o3[2], o3[3]);
}

// ---------------------------------------------------------------------------
// k2: MIXED learned | dwB, 12288 blocks x 256 thr, interleave 1:2.
//  r==0 -> learned (R12 body): 128px x 128f MFMA, no staging/barriers.
//  r>=1 -> dwB (R12 body): xt-based dw for y in [128,256).
// Per-XCD dense counters keep n = xcd, y sequential -> xt windows L2-hot.
// All out stores nontemporal (R10).
// ---------------------------------------------------------------------------
__global__ __launch_bounds__(256, 4) void k2_kernel(const unsigned short* __restrict__ wsW,
                                                    const unsigned short* __restrict__ xt,
                                                    const float* __restrict__ bl,
                                                    float* __restrict__ out) {
    __shared__ float lds_e[4][16][68];        // 17408 B, per-wave slabs (learned)

    int bid = blockIdx.x;
    int xcd = bid & 7;
    int g = bid >> 3;                         // 0..1535
    int r = g % 3;
    int cnt = g / 3;                          // 0..511 per (xcd, r)
    int n = xcd;

    if (r == 0) {
        // ================= learned block =================
        int y = cnt >> 1;
        int xs = cnt & 1;

        int tid = threadIdx.x;
        int lane = tid & 63;
        int w = tid >> 6;
        int wf = w >> 1;                      // f-half (0..1)
        int ws = w & 1;                       // px 64-segment (0..1)
        int x0 = xs * 128 + ws * 64;
        int lr = lane & 15;
        int lk = lane >> 4;

        const char* xb = reinterpret_cast<const char*>(xt) + (size_t)n * (8 * HH * WW * 16);

        int colb[4][3];
#pragma unroll
        for (int j = 0; j < 4; ++j)
#pragma unroll
            for (int dx = 0; dx < 3; ++dx)
                colb[j][dx] = clampi(x0 + j * 16 + lr + dx - 1, 0, WW - 1) * 16;

        f32x4 acc[4][4] = {};                 // [mt (16f tile)][j (16px group)]

#pragma unroll
        for (int t = 0; t < 9; ++t) {
            int dy = t / 3, dx = t - 3 * (t / 3);
            int yc = clampi(y + dy - 1, 0, HH - 1);
#pragma unroll
            for (int kk = 0; kk < 2; ++kk) {
                int kg = kk * 4 + lk;
                size_t rowoff = ((size_t)kg * HH + yc) * (WW * 16);
                bf16x8 a4[4], b4[4];
#pragma unroll
                for (int mt = 0; mt < 4; ++mt)
                    a4[mt] = *reinterpret_cast<const bf16x8*>(
                        wsW + ((size_t)(t * 8 + kg) * 128 + wf * 64 + mt * 16 + lr) * 8);
#pragma unroll
                for (int j = 0; j < 4; ++j)
                    b4[j] = *reinterpret_cast<const bf16x8*>(xb + rowoff + colb[j][dx]);
#pragma unroll
                for (int mt = 0; mt < 4; ++mt)
#pragma unroll
                    for (int j = 0; j < 4; ++j)
                        acc[mt][j] = __builtin_amdgcn_mfma_f32_16x16x32_bf16(
                            a4[mt], b4[j], acc[mt][j], 0, 0, 0);
            }
        }

        // epilogue: per-wave transpose via private LDS slab; 256B nt stores
        float* le = &lds_e[w][0][0];
#pragma unroll
        for (int mt = 0; mt < 4; ++mt) {
#pragma unroll
            for (int i = 0; i < 4; ++i) {
                int f16 = lk * 4 + i;
                float bv = bl[wf * 64 + mt * 16 + f16];
#pragma unroll
                for (int j = 0; j < 4; ++j)
                    le[f16 * 68 + j * 16 + lr] = acc[mt][j][i] + bv;
            }
#pragma unroll
            for (int p = 0; p < 4; ++p) {
                int f16 = p * 4 + lk;
                const float* s = &le[f16 * 68 + lr * 4];
                int f = wf * 64 + mt * 16 + f16;
                nts4(out + (size_t)(n * OUTC + 256 + f) * HW + (size_t)y * WW + x0 + lr * 4,
                     s[0], s[1], s[2], s[3]);
            }
        }
        return;
    }

    // ================= dwB block: xt-based dw, y in [128,256) =================
    {
        int m = (r - 1) * 512 + cnt;          // 0..1023 per xcd
        int cg = m >> 7;                      // 0..7
        int y = 128 + (m & 127);
        int w = threadIdx.x;

        const unsigned short* xg = xt + (size_t)(n * 8 + cg) * HH * WW * 8;
        int yr[3], wc[3];
#pragma unroll
        for (int d = 0; d < 3; ++d) {
            yr[d] = clampi(y + d - 1, 0, HH - 1);
            wc[d] = clampi(w + d - 1, 0, WW - 1);
        }
        uint4 chunk[3][3];
#pragma unroll
        for (int rr = 0; rr < 3; ++rr)
#pragma unroll
            for (int c = 0; c < 3; ++c)
                chunk[rr][c] = *reinterpret_cast<const uint4*>(
                    xg + ((size_t)yr[rr] * WW + wc[c]) * 8);

        size_t ob = (size_t)n * OUTC * HW + (size_t)y * WW + w;
#pragma unroll
        for (int j = 0; j < 8; ++j) {
            float v[3][3];
#pragma unroll
            for (int rr = 0; rr < 3; ++rr)
#pragma unroll
                for (int c = 0; c < 3; ++c) {
                    unsigned word = (&chunk[rr][c].x)[j >> 1];
                    v[rr][c] = bf2f((unsigned short)(j & 1 ? word >> 16 : word & 0xffff));
                }
            int ch = cg * 8 + j;
            float tL = v[0][0], tC = v[0][1], tR = v[0][2];
            float mL = v[1][0], mC = v[1][1], mR = v[1][2];
            float bL = v[2][0], bC = v[2][1], bR = v[2][2];
            float o0 = mC;
            float o1 = (tL + 2.f * tC + tR) - (bL + 2.f * bC + bR);
            float o2 = (tL - tR) + 2.f * (mL - mR) + (bL - bR);
            float o3 = 4.f * mC - tC - bC - mL - mR;
            __builtin_nontemporal_store(o0, out + ob + (size_t)(ch * 3 + 0) * HW);
            __builtin_nontemporal_store(o1, out + ob + (size_t)(ch * 3 + 1) * HW);
            __builtin_nontemporal_store(o2, out + ob + (size_t)(ch * 3 + 2) * HW);
            __builtin_nontemporal_store(o3, out + ob + (size_t)(192 + ch) * HW);
        }
    }
}

extern "C" void kernel_launch(void* const* d_in, const int* in_sizes, int n_in,
                              void* d_out, int out_size, void* d_ws, size_t ws_size,
                              hipStream_t stream) {
    const float* x  = (const float*)d_in[0];
    const float* Wl = (const float*)d_in[1];
    const float* bl = (const float*)d_in[2];
    float* out = (float*)d_out;

    unsigned short* wsW = (unsigned short*)d_ws;                            // 147456 B
    unsigned short* xt  = (unsigned short*)((char*)d_ws + 262144);          // 64 MB

    wT_kernel<<<36, 256, 0, stream>>>(Wl, wsW);
    k1_kernel<<<32768, 256, 0, stream>>>(x, xt, out);
    k2_kernel<<<12288, 256, 0, stream>>>(wsW, xt, bl, out);
}